// Round 2
// baseline (158.438 us; speedup 1.0000x reference)
//
#include <hip/hip_runtime.h>

// ============================================================================
// ESupConLoss on MI355X (gfx950)
//
// out = ( pt_loss + sum_i[ -pos_i + neg_i + 2*dot(au_i,tp_i) ] ) / (N+2)
//   pos_i = ln( sum_{j!=i} e^{au_i.au_j} + e^{tp_i.tp_j} )
//   neg_i = ln( sum_{j!=i} e^{au_i.tp_j} )
//   pt_loss = (sum_i au_i - sum_i tp_i) . (pt1 - pt0) / N
//
// log2-domain trick: inputs pre-scaled by sqrt(log2 e) and cast to bf16, so
// MFMA dots are already log2-domain and v_exp_f32 (=2^x) needs no scaling.
// Fixed shift C2=32 folded into MFMA C-init; cancels in -pos+neg.
//
// Round-2 structure: grid 1024 (4 blocks/CU target), fragment-ordered LDS
// (conflict-free linear ds_read_b128), async global_load_lds width-16
// staging, nt-paired accumulators (32 VGPRs live), last-block final write.
// ============================================================================

typedef float f32x4 __attribute__((ext_vector_type(4)));
typedef __bf16 bf16x8 __attribute__((ext_vector_type(8)));

static constexpr int   N_ROWS = 8192;
static constexpr int   DIM    = 128;
static constexpr float SQRT_LOG2E = 1.2011224087864498f; // sqrt(log2(e))
static constexpr float C2  = 32.0f;                      // log2-domain shift
static constexpr float LN2 = 0.6931471805599453f;

// ---------------- ws layout (bytes) ----------------
// zb_au : bf16[8192*128]  @ 0          (2 MiB)
// zb_tp : bf16[8192*128]  @ 2097152    (2 MiB)
// P     : f32[8192]       @ 4194304
// Ng    : f32[8192]       @ 4227072
// acc   : f32[2]          @ 4259840    (acc[0]=supcon, acc[1]=pt numerator)
// done  : u32             @ 4259848    (finalize completion counter)

__device__ inline unsigned short f2bf_rne(float x) {
    unsigned u = __builtin_bit_cast(unsigned, x);
    u += 0x7fffu + ((u >> 16) & 1u);
    return (unsigned short)(u >> 16);
}

// async 16B global -> LDS (wave-uniform LDS base + lane*16)
#define GLD16(gptr, lptr)                                                  \
    __builtin_amdgcn_global_load_lds(                                      \
        (const __attribute__((address_space(1))) void*)(gptr),             \
        (__attribute__((address_space(3))) void*)(lptr), 16, 0, 0)

// ---------------------------------------------------------------------------
// Kernel 1: convert f32 -> bf16 (scaled), zero P/Ng/acc/done.
// ---------------------------------------------------------------------------
__global__ void prep_kernel(const float* __restrict__ zau,
                            const float* __restrict__ ztp,
                            unsigned short* __restrict__ bau,
                            unsigned short* __restrict__ btp,
                            float* __restrict__ P, float* __restrict__ Ng,
                            float* __restrict__ acc, unsigned* __restrict__ done) {
    int gid  = blockIdx.x * blockDim.x + threadIdx.x;   // 0..262143
    int base = gid * 4;
    float4 a = *reinterpret_cast<const float4*>(zau + base);
    float4 t = *reinterpret_cast<const float4*>(ztp + base);
    ushort4 ua, ut;
    ua.x = f2bf_rne(a.x * SQRT_LOG2E); ua.y = f2bf_rne(a.y * SQRT_LOG2E);
    ua.z = f2bf_rne(a.z * SQRT_LOG2E); ua.w = f2bf_rne(a.w * SQRT_LOG2E);
    ut.x = f2bf_rne(t.x * SQRT_LOG2E); ut.y = f2bf_rne(t.y * SQRT_LOG2E);
    ut.z = f2bf_rne(t.z * SQRT_LOG2E); ut.w = f2bf_rne(t.w * SQRT_LOG2E);
    *reinterpret_cast<ushort4*>(bau + base) = ua;
    *reinterpret_cast<ushort4*>(btp + base) = ut;
    if (gid < N_ROWS) { P[gid] = 0.0f; Ng[gid] = 0.0f; }
    if (gid == 0)     { acc[0] = 0.0f; acc[1] = 0.0f; done[0] = 0u; }
}

// ---------------------------------------------------------------------------
// Kernel 2: the three similarity matrices -> per-row exp-sums.
// Grid 1024 = 16 col-splits (slow index, XCD/L2 locality) x 64 row-tiles.
// Block = 4 waves, wave owns 32 rows (2 m-tiles). 8 col tiles of 64 each.
//
// LDS layout (fragment order): per array, frag block (nt,k) is 1 KiB at
// offset (nt*4+k)*1024; lane slot = lane*16B (lane = quad*16 + l15).
//   -> ds_read_b128 at base+lane*16: linear banks, conflict-free
//   -> global_load_lds wave-uniform base + lane*16: exact HW shape
// MFMA 16x16x32 bf16 layouts (HW-verified):
//   A/B frag: elem j of lane -> index (lane&15), k = (lane>>4)*8 + j
//   C/D     : reg r of lane  -> row (lane>>4)*4 + r, col (lane&15)
// ---------------------------------------------------------------------------
template<bool DIAG>
__device__ inline void accum2(const f32x4 (&a)[2][2], float (&dst)[2][4],
                              int r0w, int colp, int quad, int l15) {
#pragma unroll
    for (int mt = 0; mt < 2; mt++)
#pragma unroll
        for (int nt = 0; nt < 2; nt++)
#pragma unroll
            for (int r = 0; r < 4; r++) {
                float e = __builtin_amdgcn_exp2f(a[mt][nt][r]);
                if (DIAG) {
                    int grow = r0w + mt * 16 + quad * 4 + r;
                    int gcol = colp + nt * 16 + l15;
                    if (grow == gcol) e = 0.0f;
                }
                dst[mt][r] += e;
            }
}

__global__ __launch_bounds__(256, 3)
void score_kernel(const unsigned short* __restrict__ bau,
                  const unsigned short* __restrict__ btp,
                  float* __restrict__ P, float* __restrict__ Ng) {
    __shared__ __align__(16) unsigned short ldsA[16 * 512];  // 16 KiB
    __shared__ __align__(16) unsigned short ldsT[16 * 512];  // 16 KiB

    const int tid  = threadIdx.x;
    const int lane = tid & 63;
    const int wave = tid >> 6;
    const int quad = lane >> 4;
    const int l15  = lane & 15;
    const int rb   = blockIdx.x & 63;   // row tile 0..63 (fast -> XCD spreads rows)
    const int cs   = blockIdx.x >> 6;   // col split 0..15 (slow -> L2 shares cols)
    const int r0w  = rb * 128 + wave * 32;

    // per-lane byte offset of this lane's 16B chunk within a column block:
    // row part l15*256 (row stride 256B) + quad*16
    const int laneoff = l15 * 256 + quad * 16;

    // this wave's 8 staged fragments: f = wave*8 + j -> (arr, nt, k)
    // arr = f>>4, nt = (f>>2)&3, k = f&3   (wave-uniform)

    // loop-invariant A fragments (rows of au / tp), 64 VGPRs total
    bf16x8 aAu[2][4], aTp[2][4];
#pragma unroll
    for (int mt = 0; mt < 2; mt++) {
        int row = r0w + mt * 16 + l15;
        const unsigned short* pa = bau + row * DIM + quad * 8;
        const unsigned short* pt = btp + row * DIM + quad * 8;
#pragma unroll
        for (int k = 0; k < 4; k++) {
            aAu[mt][k] = *reinterpret_cast<const bf16x8*>(pa + k * 32);
            aTp[mt][k] = *reinterpret_cast<const bf16x8*>(pt + k * 32);
        }
    }

    float sP[2][4] = {{0.f,0.f,0.f,0.f},{0.f,0.f,0.f,0.f}};
    float sN[2][4] = {{0.f,0.f,0.f,0.f},{0.f,0.f,0.f,0.f}};

    for (int ct = 0; ct < 8; ct++) {
        const int colbase = cs * 512 + ct * 64;
        __syncthreads();
        // ---- async stage: 8 fragment blocks per wave ----
#pragma unroll
        for (int j = 0; j < 8; j++) {
            const int f   = wave * 8 + j;
            const int arr = f >> 4;
            const int nt  = (f >> 2) & 3;
            const int k   = f & 3;
            const char* gb = (const char*)(arr ? btp : bau)
                           + ((size_t)(colbase + nt * 16) << 8) + (k << 6);
            unsigned short* lb = (arr ? ldsT : ldsA) + ((nt * 4 + k) << 9);
            GLD16(gb + laneoff, lb);
        }
        __syncthreads();   // drains vmcnt (global_load_lds) for all waves

        const bool diag = (colbase < r0w + 32) && (colbase + 64 > r0w);

        // ---- pass 1: s_aa (A = au rows, B = au cols), nt in pairs ----
#pragma unroll
        for (int np = 0; np < 2; np++) {
            f32x4 acc[2][2];
#pragma unroll
            for (int mt = 0; mt < 2; mt++)
#pragma unroll
                for (int nt = 0; nt < 2; nt++)
                    acc[mt][nt] = f32x4{-C2, -C2, -C2, -C2};
#pragma unroll
            for (int k = 0; k < 4; k++) {
                bf16x8 b0 = *reinterpret_cast<const bf16x8*>(
                    ldsA + (((np * 2 + 0) * 4 + k) << 9) + lane * 8);
                bf16x8 b1 = *reinterpret_cast<const bf16x8*>(
                    ldsA + (((np * 2 + 1) * 4 + k) << 9) + lane * 8);
#pragma unroll
                for (int mt = 0; mt < 2; mt++) {
                    acc[mt][0] = __builtin_amdgcn_mfma_f32_16x16x32_bf16(
                        aAu[mt][k], b0, acc[mt][0], 0, 0, 0);
                    acc[mt][1] = __builtin_amdgcn_mfma_f32_16x16x32_bf16(
                        aAu[mt][k], b1, acc[mt][1], 0, 0, 0);
                }
            }
            if (diag) accum2<true >(acc, sP, r0w, colbase + np * 32, quad, l15);
            else      accum2<false>(acc, sP, r0w, colbase + np * 32, quad, l15);
        }

        // ---- pass 2: s_tt and s_at share tp B-fragments, nt in pairs ----
#pragma unroll
        for (int np = 0; np < 2; np++) {
            f32x4 aT[2][2], aX[2][2];
#pragma unroll
            for (int mt = 0; mt < 2; mt++)
#pragma unroll
                for (int nt = 0; nt < 2; nt++) {
                    aT[mt][nt] = f32x4{-C2, -C2, -C2, -C2};
                    aX[mt][nt] = f32x4{-C2, -C2, -C2, -C2};
                }
#pragma unroll
            for (int k = 0; k < 4; k++) {
                bf16x8 b0 = *reinterpret_cast<const bf16x8*>(
                    ldsT + (((np * 2 + 0) * 4 + k) << 9) + lane * 8);
                bf16x8 b1 = *reinterpret_cast<const bf16x8*>(
                    ldsT + (((np * 2 + 1) * 4 + k) << 9) + lane * 8);
#pragma unroll
                for (int mt = 0; mt < 2; mt++) {
                    aT[mt][0] = __builtin_amdgcn_mfma_f32_16x16x32_bf16(
                        aTp[mt][k], b0, aT[mt][0], 0, 0, 0);
                    aX[mt][0] = __builtin_amdgcn_mfma_f32_16x16x32_bf16(
                        aAu[mt][k], b0, aX[mt][0], 0, 0, 0);
                    aT[mt][1] = __builtin_amdgcn_mfma_f32_16x16x32_bf16(
                        aTp[mt][k], b1, aT[mt][1], 0, 0, 0);
                    aX[mt][1] = __builtin_amdgcn_mfma_f32_16x16x32_bf16(
                        aAu[mt][k], b1, aX[mt][1], 0, 0, 0);
                }
            }
            if (diag) { accum2<true >(aT, sP, r0w, colbase + np * 32, quad, l15);
                        accum2<true >(aX, sN, r0w, colbase + np * 32, quad, l15); }
            else      { accum2<false>(aT, sP, r0w, colbase + np * 32, quad, l15);
                        accum2<false>(aX, sN, r0w, colbase + np * 32, quad, l15); }
        }
    }

    // ---- reduce across the 16 lanes of each quad, one atomic per row ----
#pragma unroll
    for (int mt = 0; mt < 2; mt++)
#pragma unroll
        for (int r = 0; r < 4; r++) {
            float p = sP[mt][r], ng = sN[mt][r];
            for (int m = 1; m < 16; m <<= 1) {
                p  += __shfl_xor(p,  m, 64);
                ng += __shfl_xor(ng, m, 64);
            }
            if (l15 == 0) {
                int row = r0w + mt * 16 + quad * 4 + r;
                atomicAdd(&P[row],  p);
                atomicAdd(&Ng[row], ng);
            }
        }
}

// ---------------------------------------------------------------------------
// Kernel 3: per-row  ln2*(log2 Ng - log2 P) + 2*dot(au_i,tp_i), plus the
// pt numerator sum_i (au_i - tp_i).(pt1-pt0). One wave per 8 rows.
// Last finishing block writes the final scalar (device-scope counter).
// ---------------------------------------------------------------------------
__global__ void finalize_kernel(const float* __restrict__ zau,
                                const float* __restrict__ ztp,
                                const float* __restrict__ fc,
                                const float* __restrict__ P,
                                const float* __restrict__ Ng,
                                float* __restrict__ acc,
                                unsigned* __restrict__ done,
                                float* __restrict__ out) {
    int tid     = threadIdx.x;
    int lane    = tid & 63;
    int wave_id = blockIdx.x * 4 + (tid >> 6);   // 0..1023

    float2 w0 = *reinterpret_cast<const float2*>(fc + 2 * lane);        // pt0
    float2 w1 = *reinterpret_cast<const float2*>(fc + 256 + 2 * lane);  // pt1
    float wx = w1.x - w0.x, wy = w1.y - w0.y;

    float ptp = 0.0f, ssum = 0.0f;
    for (int j = 0; j < 8; j++) {
        int i = wave_id * 8 + j;
        float2 a = *reinterpret_cast<const float2*>(zau + i * DIM + 2 * lane);
        float2 t = *reinterpret_cast<const float2*>(ztp + i * DIM + 2 * lane);
        float d = a.x * t.x + a.y * t.y;
        ptp += (a.x - t.x) * wx + (a.y - t.y) * wy;
        for (int m = 1; m < 64; m <<= 1) d += __shfl_xor(d, m, 64);
        if (lane == 0) {
            float c = LN2 * (__builtin_amdgcn_logf(Ng[i]) -
                             __builtin_amdgcn_logf(P[i])) + 2.0f * d;
            ssum += c;
        }
    }
    for (int m = 1; m < 64; m <<= 1) ptp += __shfl_xor(ptp, m, 64);
    if (lane == 0) {
        atomicAdd(&acc[0], ssum);
        atomicAdd(&acc[1], ptp);
    }

    __syncthreads();
    if (tid == 0) {
        __threadfence();
        unsigned ticket = atomicAdd(done, 1u);
        if (ticket == gridDim.x - 1) {
            float a0 = atomicAdd(&acc[0], 0.0f);   // coherent read
            float a1 = atomicAdd(&acc[1], 0.0f);
            out[0] = (a1 / (float)N_ROWS + a0) / (float)(N_ROWS + 2);
        }
    }
}

extern "C" void kernel_launch(void* const* d_in, const int* in_sizes, int n_in,
                              void* d_out, int out_size, void* d_ws, size_t ws_size,
                              hipStream_t stream) {
    const float* zau = (const float*)d_in[0];
    const float* ztp = (const float*)d_in[1];
    const float* fc  = (const float*)d_in[2];
    // d_in[3] = labels (unused by the math)
    float* out = (float*)d_out;

    char* ws = (char*)d_ws;
    unsigned short* bau = (unsigned short*)(ws);
    unsigned short* btp = (unsigned short*)(ws + 2097152);
    float*    P    = (float*)(ws + 4194304);
    float*    Ng   = (float*)(ws + 4227072);
    float*    acc  = (float*)(ws + 4259840);
    unsigned* done = (unsigned*)(ws + 4259848);

    prep_kernel<<<dim3(1024), dim3(256), 0, stream>>>(zau, ztp, bau, btp, P, Ng, acc, done);
    score_kernel<<<dim3(1024), dim3(256), 0, stream>>>(bau, btp, P, Ng);
    finalize_kernel<<<dim3(256), dim3(256), 0, stream>>>(zau, ztp, fc, P, Ng, acc, done, out);
}

// Round 3
// 155.537 us; speedup vs baseline: 1.0187x; 1.0187x over previous
//
#include <hip/hip_runtime.h>

// ============================================================================
// ESupConLoss on MI355X (gfx950)
//
// out = ( pt_loss + sum_i[ -pos_i + neg_i + 2*dot(au_i,tp_i) ] ) / (N+2)
//   pos_i = ln( sum_{j!=i} e^{au_i.au_j} + e^{tp_i.tp_j} )
//   neg_i = ln( sum_{j!=i} e^{au_i.tp_j} )
//   pt_loss = (sum_i au_i - sum_i tp_i) . (pt1 - pt0) / N
//
// log2-domain trick: inputs pre-scaled by sqrt(log2 e), cast bf16; MFMA dots
// are log2-domain, v_exp_f32 (=2^x) needs no scaling. Shift C2=32 folded into
// MFMA C-init, cancels in -pos+neg.
//
// Round-3: 16 KiB LDS (32-col tiles) to probe/raise block residency;
// software-pipelined exp of previous tile's accumulators placed between
// global_load_lds issue and the drain barrier (hides drain, breaks the
// MFMA-phase/exp-phase lockstep that capped pipes at ~30%).
// ============================================================================

typedef float f32x4 __attribute__((ext_vector_type(4)));
typedef __bf16 bf16x8 __attribute__((ext_vector_type(8)));

static constexpr int   N_ROWS = 8192;
static constexpr int   DIM    = 128;
static constexpr float SQRT_LOG2E = 1.2011224087864498f; // sqrt(log2(e))
static constexpr float C2  = 32.0f;                      // log2-domain shift
static constexpr float LN2 = 0.6931471805599453f;

// ---------------- ws layout (bytes) ----------------
// zb_au : bf16[8192*128]  @ 0          (2 MiB)
// zb_tp : bf16[8192*128]  @ 2097152    (2 MiB)
// P     : f32[8192]       @ 4194304
// Ng    : f32[8192]       @ 4227072
// acc   : f32[2]          @ 4259840
// done  : u32             @ 4259848

__device__ inline unsigned short f2bf_rne(float x) {
    unsigned u = __builtin_bit_cast(unsigned, x);
    u += 0x7fffu + ((u >> 16) & 1u);
    return (unsigned short)(u >> 16);
}

#define GLD16(gptr, lptr)                                                  \
    __builtin_amdgcn_global_load_lds(                                      \
        (const __attribute__((address_space(1))) void*)(gptr),             \
        (__attribute__((address_space(3))) void*)(lptr), 16, 0, 0)

// ---------------------------------------------------------------------------
// Kernel 1: convert f32 -> bf16 (scaled), zero P/Ng/acc/done.
// ---------------------------------------------------------------------------
__global__ void prep_kernel(const float* __restrict__ zau,
                            const float* __restrict__ ztp,
                            unsigned short* __restrict__ bau,
                            unsigned short* __restrict__ btp,
                            float* __restrict__ P, float* __restrict__ Ng,
                            float* __restrict__ acc, unsigned* __restrict__ done) {
    int gid  = blockIdx.x * blockDim.x + threadIdx.x;   // 0..262143
    int base = gid * 4;
    float4 a = *reinterpret_cast<const float4*>(zau + base);
    float4 t = *reinterpret_cast<const float4*>(ztp + base);
    ushort4 ua, ut;
    ua.x = f2bf_rne(a.x * SQRT_LOG2E); ua.y = f2bf_rne(a.y * SQRT_LOG2E);
    ua.z = f2bf_rne(a.z * SQRT_LOG2E); ua.w = f2bf_rne(a.w * SQRT_LOG2E);
    ut.x = f2bf_rne(t.x * SQRT_LOG2E); ut.y = f2bf_rne(t.y * SQRT_LOG2E);
    ut.z = f2bf_rne(t.z * SQRT_LOG2E); ut.w = f2bf_rne(t.w * SQRT_LOG2E);
    *reinterpret_cast<ushort4*>(bau + base) = ua;
    *reinterpret_cast<ushort4*>(btp + base) = ut;
    if (gid < N_ROWS) { P[gid] = 0.0f; Ng[gid] = 0.0f; }
    if (gid == 0)     { acc[0] = 0.0f; acc[1] = 0.0f; done[0] = 0u; }
}

// ---------------------------------------------------------------------------
// Kernel 2. Grid 1024 = 16 col-splits (slow) x 64 row-tiles (fast).
// Block = 4 waves, wave owns 32 rows. 16 col tiles of 32 cols each.
// LDS: 16 fragment blocks of 1 KiB (arr,nt{0,1},k{0..3}) = 16 KiB.
//   frag f = arr*8 + nt*4 + k at ushort offset f*512; lane slot = lane*16B.
// MFMA 16x16x32 bf16 layouts (HW-verified round 2, absmax 0):
//   A/B frag: elem j of lane -> index (lane&15), k = (lane>>4)*8 + j
//   C/D     : reg r of lane  -> row (lane>>4)*4 + r, col (lane&15)
// Pipeline per ct: [barrier][issue 4 GLDs][exp prev pending][barrier][MFMA]
// ---------------------------------------------------------------------------
template<bool DIAG>
__device__ inline void expacc(const f32x4 (&a)[2][2], float (&dst)[2][4],
                              int r0w, int colp, int quad, int l15) {
#pragma unroll
    for (int mt = 0; mt < 2; mt++)
#pragma unroll
        for (int nt = 0; nt < 2; nt++)
#pragma unroll
            for (int r = 0; r < 4; r++) {
                float e = __builtin_amdgcn_exp2f(a[mt][nt][r]);
                if (DIAG) {
                    int grow = r0w + mt * 16 + quad * 4 + r;
                    int gcol = colp + nt * 16 + l15;
                    if (grow == gcol) e = 0.0f;
                }
                dst[mt][r] += e;
            }
}

__global__ __launch_bounds__(256, 3)
void score_kernel(const unsigned short* __restrict__ bau,
                  const unsigned short* __restrict__ btp,
                  float* __restrict__ P, float* __restrict__ Ng) {
    __shared__ __align__(16) unsigned short lds[16 * 512];   // 16 KiB

    const int tid  = threadIdx.x;
    const int lane = tid & 63;
    const int wave = tid >> 6;
    const int quad = lane >> 4;
    const int l15  = lane & 15;
    const int rb   = blockIdx.x & 63;   // row tile (fast -> spreads over XCDs)
    const int cs   = blockIdx.x >> 6;   // col split (slow -> shares col panel)
    const int r0w  = rb * 128 + wave * 32;

    const int laneoff = l15 * 256 + quad * 16;   // per-lane global byte offset

    // loop-invariant A fragments (rows of au / tp), 64 VGPRs
    bf16x8 aAu[2][4], aTp[2][4];
#pragma unroll
    for (int mt = 0; mt < 2; mt++) {
        int row = r0w + mt * 16 + l15;
        const unsigned short* pa = bau + row * DIM + quad * 8;
        const unsigned short* pt = btp + row * DIM + quad * 8;
#pragma unroll
        for (int k = 0; k < 4; k++) {
            aAu[mt][k] = *reinterpret_cast<const bf16x8*>(pa + k * 32);
            aTp[mt][k] = *reinterpret_cast<const bf16x8*>(pt + k * 32);
        }
    }

    float sP[2][4] = {{0.f,0.f,0.f,0.f},{0.f,0.f,0.f,0.f}};
    float sN[2][4] = {{0.f,0.f,0.f,0.f},{0.f,0.f,0.f,0.f}};

    // pending accumulators (survive across ct iterations)
    f32x4 pAA[2][2], pTT[2][2], pAT[2][2];
#pragma unroll
    for (int mt = 0; mt < 2; mt++)
#pragma unroll
        for (int nt = 0; nt < 2; nt++) {
            pAA[mt][nt] = f32x4{-C2, -C2, -C2, -C2};
            pTT[mt][nt] = f32x4{-C2, -C2, -C2, -C2};
            pAT[mt][nt] = f32x4{-C2, -C2, -C2, -C2};
        }
    int prevcol = -100000;   // first-round pendings are 2^-32 dummies

    for (int ct = 0; ct < 16; ct++) {
        const int colbase = cs * 512 + ct * 32;

        __syncthreads();   // all waves done reading previous tile
        // ---- issue async staging for this tile (4 frag blocks / wave) ----
#pragma unroll
        for (int j = 0; j < 4; j++) {
            const int f   = wave * 4 + j;        // 0..15
            const int arr = f >> 3;
            const int nt  = (f >> 2) & 1;
            const int k   = f & 3;
            const char* gb = (const char*)(arr ? btp : bau)
                           + ((size_t)(colbase + nt * 16) << 8) + (k << 6);
            GLD16(gb + laneoff, lds + (f << 9));
        }

        // ---- exp-process PREVIOUS tile's pendings (hides GLD drain) ----
        {
            const bool pd = (prevcol < r0w + 32) && (prevcol + 32 > r0w);
            if (pd) {
                expacc<true >(pAA, sP, r0w, prevcol, quad, l15);
                expacc<true >(pTT, sP, r0w, prevcol, quad, l15);
                expacc<true >(pAT, sN, r0w, prevcol, quad, l15);
            } else {
                expacc<false>(pAA, sP, r0w, prevcol, quad, l15);
                expacc<false>(pTT, sP, r0w, prevcol, quad, l15);
                expacc<false>(pAT, sN, r0w, prevcol, quad, l15);
            }
        }
#pragma unroll
        for (int mt = 0; mt < 2; mt++)
#pragma unroll
            for (int nt = 0; nt < 2; nt++) {
                pAA[mt][nt] = f32x4{-C2, -C2, -C2, -C2};
                pTT[mt][nt] = f32x4{-C2, -C2, -C2, -C2};
                pAT[mt][nt] = f32x4{-C2, -C2, -C2, -C2};
            }

        __syncthreads();   // staged data visible (vmcnt drained)

        // ---- pure-MFMA section: s_aa then s_tt/s_at (shared tp frags) ----
#pragma unroll
        for (int k = 0; k < 4; k++) {
            bf16x8 b0 = *reinterpret_cast<const bf16x8*>(lds + ((0 + k) << 9) + lane * 8);
            bf16x8 b1 = *reinterpret_cast<const bf16x8*>(lds + ((4 + k) << 9) + lane * 8);
#pragma unroll
            for (int mt = 0; mt < 2; mt++) {
                pAA[mt][0] = __builtin_amdgcn_mfma_f32_16x16x32_bf16(
                    aAu[mt][k], b0, pAA[mt][0], 0, 0, 0);
                pAA[mt][1] = __builtin_amdgcn_mfma_f32_16x16x32_bf16(
                    aAu[mt][k], b1, pAA[mt][1], 0, 0, 0);
            }
        }
#pragma unroll
        for (int k = 0; k < 4; k++) {
            bf16x8 t0 = *reinterpret_cast<const bf16x8*>(lds + ((8  + k) << 9) + lane * 8);
            bf16x8 t1 = *reinterpret_cast<const bf16x8*>(lds + ((12 + k) << 9) + lane * 8);
#pragma unroll
            for (int mt = 0; mt < 2; mt++) {
                pTT[mt][0] = __builtin_amdgcn_mfma_f32_16x16x32_bf16(
                    aTp[mt][k], t0, pTT[mt][0], 0, 0, 0);
                pAT[mt][0] = __builtin_amdgcn_mfma_f32_16x16x32_bf16(
                    aAu[mt][k], t0, pAT[mt][0], 0, 0, 0);
                pTT[mt][1] = __builtin_amdgcn_mfma_f32_16x16x32_bf16(
                    aTp[mt][k], t1, pTT[mt][1], 0, 0, 0);
                pAT[mt][1] = __builtin_amdgcn_mfma_f32_16x16x32_bf16(
                    aAu[mt][k], t1, pAT[mt][1], 0, 0, 0);
            }
        }
        prevcol = colbase;
    }

    // ---- tail: exp-process last tile's pendings ----
    {
        const bool pd = (prevcol < r0w + 32) && (prevcol + 32 > r0w);
        if (pd) {
            expacc<true >(pAA, sP, r0w, prevcol, quad, l15);
            expacc<true >(pTT, sP, r0w, prevcol, quad, l15);
            expacc<true >(pAT, sN, r0w, prevcol, quad, l15);
        } else {
            expacc<false>(pAA, sP, r0w, prevcol, quad, l15);
            expacc<false>(pTT, sP, r0w, prevcol, quad, l15);
            expacc<false>(pAT, sN, r0w, prevcol, quad, l15);
        }
    }

    // ---- reduce across the 16 lanes of each quad, one atomic per row ----
#pragma unroll
    for (int mt = 0; mt < 2; mt++)
#pragma unroll
        for (int r = 0; r < 4; r++) {
            float p = sP[mt][r], ng = sN[mt][r];
            for (int m = 1; m < 16; m <<= 1) {
                p  += __shfl_xor(p,  m, 64);
                ng += __shfl_xor(ng, m, 64);
            }
            if (l15 == 0) {
                int row = r0w + mt * 16 + quad * 4 + r;
                atomicAdd(&P[row],  p);
                atomicAdd(&Ng[row], ng);
            }
        }
}

// ---------------------------------------------------------------------------
// Kernel 3: per-row  ln2*(log2 Ng - log2 P) + 2*dot(au_i,tp_i), plus the
// pt numerator. Last finishing block writes the final scalar.
// ---------------------------------------------------------------------------
__global__ void finalize_kernel(const float* __restrict__ zau,
                                const float* __restrict__ ztp,
                                const float* __restrict__ fc,
                                const float* __restrict__ P,
                                const float* __restrict__ Ng,
                                float* __restrict__ acc,
                                unsigned* __restrict__ done,
                                float* __restrict__ out) {
    int tid     = threadIdx.x;
    int lane    = tid & 63;
    int wave_id = blockIdx.x * 4 + (tid >> 6);   // 0..1023

    float2 w0 = *reinterpret_cast<const float2*>(fc + 2 * lane);        // pt0
    float2 w1 = *reinterpret_cast<const float2*>(fc + 256 + 2 * lane);  // pt1
    float wx = w1.x - w0.x, wy = w1.y - w0.y;

    float ptp = 0.0f, ssum = 0.0f;
    for (int j = 0; j < 8; j++) {
        int i = wave_id * 8 + j;
        float2 a = *reinterpret_cast<const float2*>(zau + i * DIM + 2 * lane);
        float2 t = *reinterpret_cast<const float2*>(ztp + i * DIM + 2 * lane);
        float d = a.x * t.x + a.y * t.y;
        ptp += (a.x - t.x) * wx + (a.y - t.y) * wy;
        for (int m = 1; m < 64; m <<= 1) d += __shfl_xor(d, m, 64);
        if (lane == 0) {
            float c = LN2 * (__builtin_amdgcn_logf(Ng[i]) -
                             __builtin_amdgcn_logf(P[i])) + 2.0f * d;
            ssum += c;
        }
    }
    for (int m = 1; m < 64; m <<= 1) ptp += __shfl_xor(ptp, m, 64);
    if (lane == 0) {
        atomicAdd(&acc[0], ssum);
        atomicAdd(&acc[1], ptp);
    }

    __syncthreads();
    if (tid == 0) {
        __threadfence();
        unsigned ticket = atomicAdd(done, 1u);
        if (ticket == gridDim.x - 1) {
            float a0 = atomicAdd(&acc[0], 0.0f);   // coherent read
            float a1 = atomicAdd(&acc[1], 0.0f);
            out[0] = (a1 / (float)N_ROWS + a0) / (float)(N_ROWS + 2);
        }
    }
}

extern "C" void kernel_launch(void* const* d_in, const int* in_sizes, int n_in,
                              void* d_out, int out_size, void* d_ws, size_t ws_size,
                              hipStream_t stream) {
    const float* zau = (const float*)d_in[0];
    const float* ztp = (const float*)d_in[1];
    const float* fc  = (const float*)d_in[2];
    // d_in[3] = labels (unused by the math)
    float* out = (float*)d_out;

    char* ws = (char*)d_ws;
    unsigned short* bau = (unsigned short*)(ws);
    unsigned short* btp = (unsigned short*)(ws + 2097152);
    float*    P    = (float*)(ws + 4194304);
    float*    Ng   = (float*)(ws + 4227072);
    float*    acc  = (float*)(ws + 4259840);
    unsigned* done = (unsigned*)(ws + 4259848);

    prep_kernel<<<dim3(1024), dim3(256), 0, stream>>>(zau, ztp, bau, btp, P, Ng, acc, done);
    score_kernel<<<dim3(1024), dim3(256), 0, stream>>>(bau, btp, P, Ng);
    finalize_kernel<<<dim3(256), dim3(256), 0, stream>>>(zau, ztp, fc, P, Ng, acc, done, out);
}